// Round 2
// baseline (90.235 us; speedup 1.0000x reference)
//
#include <hip/hip_runtime.h>

#define T        64     // num_thetas
#define S        32     // bump_steps
#define CHUNK    128    // nodes per block
#define SPT      8      // s-values per thread (256 threads = 4 waves x 64 lanes)

// Each block: 128 contiguous nodes. lane = theta t, wave = s-group (8 s each).
// sigmoid(100*(lin_s - nh)) = 1/(1 + exp2((nh - lin_s)*100*log2(e)))
// lin uniformly spaced => e_s geometric: ONE exp2 per (node,thread), 8 rcp.
// batch is sorted: most 128-node chunks live in one graph -> branch-free
// unrolled fast path; rare boundary chunks take the per-node-check path.
__global__ __launch_bounds__(256) void ect_kernel(
    const float* __restrict__ x, const float* __restrict__ v,
    const float* __restrict__ lin, const int* __restrict__ batch,
    float* __restrict__ out, int n_points)
{
    __shared__ float sx[CHUNK * 3];
    __shared__ int   sb[CHUNK];

    const int tid = threadIdx.x;
    const int t   = tid & 63;
    const int s0  = (tid >> 6) * SPT;

    const float K = 144.26950408889634f;  // 100 * log2(e)

    const float v0 = v[0 * T + t];
    const float v1 = v[1 * T + t];
    const float v2 = v[2 * T + t];

    const float c0 = lin[s0] * K;
    const float m  = __builtin_amdgcn_exp2f((lin[0] - lin[1]) * K);

    const int base = blockIdx.x * CHUNK;
    const int rem  = min(CHUNK, n_points - base);

    if (rem == CHUNK) {
        // vectorized staging: 128*3 floats = 96 float4 (base*3 % 4 == 0)
        const float4* xv = (const float4*)(x + base * 3);
        if (tid < CHUNK * 3 / 4) ((float4*)sx)[tid] = xv[tid];
        if (tid < CHUNK)         sb[tid] = batch[base + tid];
    } else {
        for (int i = tid; i < rem * 3; i += 256) sx[i] = x[base * 3 + i];
        for (int i = tid; i < rem;     i += 256) sb[i] = batch[base + i];
    }
    __syncthreads();

    float acc[SPT];
#pragma unroll
    for (int j = 0; j < SPT; j++) acc[j] = 0.0f;

    const bool single = (sb[0] == sb[rem - 1]);   // block-uniform

    if (single && rem == CHUNK) {
        // fast path: no per-node branch; unroll 4 -> 4 independent exp/rcp
        // chains hide the serial e*=m latency and LDS read waits
#pragma unroll 4
        for (int n = 0; n < CHUNK; n++) {
            const float nh = sx[n * 3 + 0] * v0 + sx[n * 3 + 1] * v1 + sx[n * 3 + 2] * v2;
            float e = __builtin_amdgcn_exp2f(nh * K - c0);  // inf/0 saturate correctly
#pragma unroll
            for (int j = 0; j < SPT; j++) {
                acc[j] += __builtin_amdgcn_rcpf(1.0f + e);
                e *= m;
            }
        }
        float* o = out + (sb[0] * S + s0) * T + t;
#pragma unroll
        for (int j = 0; j < SPT; j++) atomicAdd(o + j * T, acc[j]);
    } else {
        // boundary path: per-node graph check
        int cur = sb[0];
        for (int n = 0; n < rem; n++) {
            const int b = sb[n];
            if (b != cur) {
                float* o = out + (cur * S + s0) * T + t;
#pragma unroll
                for (int j = 0; j < SPT; j++) {
                    atomicAdd(o + j * T, acc[j]);
                    acc[j] = 0.0f;
                }
                cur = b;
            }
            const float nh = sx[n * 3 + 0] * v0 + sx[n * 3 + 1] * v1 + sx[n * 3 + 2] * v2;
            float e = __builtin_amdgcn_exp2f(nh * K - c0);
#pragma unroll
            for (int j = 0; j < SPT; j++) {
                acc[j] += __builtin_amdgcn_rcpf(1.0f + e);
                e *= m;
            }
        }
        float* o = out + (cur * S + s0) * T + t;
#pragma unroll
        for (int j = 0; j < SPT; j++) atomicAdd(o + j * T, acc[j]);
    }
}

extern "C" void kernel_launch(void* const* d_in, const int* in_sizes, int n_in,
                              void* d_out, int out_size, void* d_ws, size_t ws_size,
                              hipStream_t stream) {
    const float* x     = (const float*)d_in[0];   // [N,3]
    const float* v     = (const float*)d_in[1];   // [3,64]
    const float* lin   = (const float*)d_in[2];   // [32]
    const int*   batch = (const int*)d_in[3];     // [N], sorted
    float* out = (float*)d_out;                   // [64,32,64]

    const int n_points = in_sizes[0] / 3;
    const int blocks   = (n_points + CHUNK - 1) / CHUNK;

    // harness poisons d_out with 0xAA before every timed replay
    hipMemsetAsync(d_out, 0, (size_t)out_size * sizeof(float), stream);
    ect_kernel<<<blocks, 256, 0, stream>>>(x, v, lin, batch, out, n_points);
}

// Round 3
// 82.026 us; speedup vs baseline: 1.1001x; 1.1001x over previous
//
#include <hip/hip_runtime.h>

#define T        64     // num_thetas
#define S        32     // bump_steps
#define CHUNK    32     // nodes per block (small => 2048 blocks => 8 waves/SIMD)
#define SPT      8      // s-values per thread (256 threads = 4 waves x 64 lanes)

// lane = theta t, wave = s-group (8 s per thread).
// sigmoid(100*(lin_s - nh)) = 1/(1 + exp2((nh - lin_s)*100*log2(e)))
// lin uniformly spaced => e_s geometric: ONE exp2 per (node,thread), 8 rcp.
// Trans-unit bound: 9 trans-ops/node/wave; needs 8 waves/SIMD to saturate.
__global__ __launch_bounds__(256, 8) void ect_kernel(
    const float* __restrict__ x, const float* __restrict__ v,
    const float* __restrict__ lin, const int* __restrict__ batch,
    float* __restrict__ out, int n_points)
{
    __shared__ float sx[CHUNK * 3];
    __shared__ int   sb[CHUNK];

    const int tid = threadIdx.x;
    const int t   = tid & 63;
    const int s0  = (tid >> 6) * SPT;

    const float K = 144.26950408889634f;  // 100 * log2(e)

    const float v0 = v[0 * T + t];
    const float v1 = v[1 * T + t];
    const float v2 = v[2 * T + t];

    const float c0 = lin[s0] * K;
    const float m  = __builtin_amdgcn_exp2f((lin[0] - lin[1]) * K); // < 1

    const int base = blockIdx.x * CHUNK;
    const int rem  = min(CHUNK, n_points - base);

    if (rem == CHUNK) {
        // 32 nodes * 3 floats = 24 float4 (16B-aligned: base*12 % 16 == 0)
        if (tid < CHUNK * 3 / 4) ((float4*)sx)[tid] = ((const float4*)(x + base * 3))[tid];
        if (tid < CHUNK)         sb[tid] = batch[base + tid];
    } else {
        for (int i = tid; i < rem * 3; i += 256) sx[i] = x[base * 3 + i];
        for (int i = tid; i < rem;     i += 256) sb[i] = batch[base + i];
    }
    __syncthreads();

    float acc[SPT];
#pragma unroll
    for (int j = 0; j < SPT; j++) acc[j] = 0.0f;

    int cur = sb[0];
#pragma unroll 2
    for (int n = 0; n < rem; n++) {
        const int b = sb[n];            // block-uniform scalar
        if (b != cur) {                 // graph boundary: ~63 of 2048 blocks, once
            float* o = out + (cur * S + s0) * T + t;
#pragma unroll
            for (int j = 0; j < SPT; j++) {
                atomicAdd(o + j * T, acc[j]);
                acc[j] = 0.0f;
            }
            cur = b;
        }
        const float nh = sx[n * 3 + 0] * v0 + sx[n * 3 + 1] * v1 + sx[n * 3 + 2] * v2;
        float e = __builtin_amdgcn_exp2f(nh * K - c0);  // inf/0 saturate correctly
#pragma unroll
        for (int j = 0; j < SPT; j++) {
            acc[j] += __builtin_amdgcn_rcpf(1.0f + e);
            e *= m;
        }
    }
    float* o = out + (cur * S + s0) * T + t;
#pragma unroll
    for (int j = 0; j < SPT; j++) atomicAdd(o + j * T, acc[j]);
}

extern "C" void kernel_launch(void* const* d_in, const int* in_sizes, int n_in,
                              void* d_out, int out_size, void* d_ws, size_t ws_size,
                              hipStream_t stream) {
    const float* x     = (const float*)d_in[0];   // [N,3]
    const float* v     = (const float*)d_in[1];   // [3,64]
    const float* lin   = (const float*)d_in[2];   // [32]
    const int*   batch = (const int*)d_in[3];     // [N], sorted
    float* out = (float*)d_out;                   // [64,32,64]

    const int n_points = in_sizes[0] / 3;
    const int blocks   = (n_points + CHUNK - 1) / CHUNK;

    hipMemsetAsync(d_out, 0, (size_t)out_size * sizeof(float), stream);
    ect_kernel<<<blocks, 256, 0, stream>>>(x, v, lin, batch, out, n_points);
}